// Round 14
// baseline (139.227 us; speedup 1.0000x reference)
//
#include <hip/hip_runtime.h>
#include <hip/hip_bf16.h>
#include <hip/hip_fp16.h>

#define IN_DIM 128
#define HID 8
#define TW 256        // node tile width (sort + CSR granularity)
#define MAXT 512      // max tiles (N<=131072)
#define CCH 256       // edge chunks (one 1024-thread block each)
#define CAPS 128      // src bucket capacity per (chunk,tile): bytes, 64B-aligned runs
#define CAPD 96       // dst bucket capacity per (chunk,tile): uints, 384B runs (64B-aligned)
#define TILECAP 12288 // per-tile sorted-list capacity (tile len ~Pois(8192), +45 sigma)

// ---------------- scatterAB2: direct bucketing into fixed-capacity regions ----------------
// slot = tile_region + chunk*CAP + local_idx (local_idx via LDS returning atomic).
// No counting pass / scan needed; per-(tile,chunk) counts written at end (tile-major).
__global__ __launch_bounds__(1024) void scatterAB2_kernel(const int* __restrict__ src, const int* __restrict__ dst,
        unsigned char* __restrict__ bucket_s, unsigned int* __restrict__ bucketT,
        int* __restrict__ cntS_t, int* __restrict__ cntD_t, int E, int RT, int chunk) {
    __shared__ int os[MAXT], od[MAXT];
    int t = threadIdx.x, c = blockIdx.x;
    for (int i = t; i < RT; i += 1024) { os[i] = 0; od[i] = 0; }
    __syncthreads();
    int lo = c * chunk, hi = min(lo + chunk, E);
    if (lo < hi) {
        const int4* s4 = reinterpret_cast<const int4*>(src);
        const int4* d4 = reinterpret_cast<const int4*>(dst);
        int q0 = lo >> 2, q1 = hi >> 2;
        for (int q = q0 + t; q < q1; q += 1024) {
            int4 s = s4[q], d = d4[q];
            int p;
            p = atomicAdd(&os[s.x >> 8], 1); if (p < CAPS) bucket_s[(size_t)(s.x >> 8) * (CCH * CAPS) + c * CAPS + p] = (unsigned char)(s.x & 255);
            p = atomicAdd(&os[s.y >> 8], 1); if (p < CAPS) bucket_s[(size_t)(s.y >> 8) * (CCH * CAPS) + c * CAPS + p] = (unsigned char)(s.y & 255);
            p = atomicAdd(&os[s.z >> 8], 1); if (p < CAPS) bucket_s[(size_t)(s.z >> 8) * (CCH * CAPS) + c * CAPS + p] = (unsigned char)(s.z & 255);
            p = atomicAdd(&os[s.w >> 8], 1); if (p < CAPS) bucket_s[(size_t)(s.w >> 8) * (CCH * CAPS) + c * CAPS + p] = (unsigned char)(s.w & 255);
            p = atomicAdd(&od[d.x >> 8], 1); if (p < CAPD) bucketT[(size_t)(d.x >> 8) * (CCH * CAPD) + c * CAPD + p] = ((unsigned)s.x << 8) | (unsigned)(d.x & 255);
            p = atomicAdd(&od[d.y >> 8], 1); if (p < CAPD) bucketT[(size_t)(d.y >> 8) * (CCH * CAPD) + c * CAPD + p] = ((unsigned)s.y << 8) | (unsigned)(d.y & 255);
            p = atomicAdd(&od[d.z >> 8], 1); if (p < CAPD) bucketT[(size_t)(d.z >> 8) * (CCH * CAPD) + c * CAPD + p] = ((unsigned)s.z << 8) | (unsigned)(d.z & 255);
            p = atomicAdd(&od[d.w >> 8], 1); if (p < CAPD) bucketT[(size_t)(d.w >> 8) * (CCH * CAPD) + c * CAPD + p] = ((unsigned)s.w << 8) | (unsigned)(d.w & 255);
        }
        for (int i = (q1 << 2) + t; i < hi; i += 1024) {
            int s = src[i], d = dst[i];
            int p = atomicAdd(&os[s >> 8], 1);
            if (p < CAPS) bucket_s[(size_t)(s >> 8) * (CCH * CAPS) + c * CAPS + p] = (unsigned char)(s & 255);
            p = atomicAdd(&od[d >> 8], 1);
            if (p < CAPD) bucketT[(size_t)(d >> 8) * (CCH * CAPD) + c * CAPD + p] = ((unsigned)s << 8) | (unsigned)(d & 255);
        }
    }
    __syncthreads();
    for (int i = t; i < RT; i += 1024) {
        cntS_t[(size_t)i * CCH + c] = min(os[i], CAPS);
        cntD_t[(size_t)i * CCH + c] = min(od[i], CAPD);
    }
}

// ---------------- conv1deg2: region-read degree hist + conv1 -> deg_out, h4 ----------------
__global__ __launch_bounds__(512) void conv1deg2_kernel(
        const unsigned char* __restrict__ bucket_s, const int* __restrict__ cntS_t,
        const float* __restrict__ x, const float* __restrict__ W1,
        float* __restrict__ deg_out, uint4* __restrict__ h4, int N) {
    __shared__ float wt[HID * 132];
    __shared__ int cnt[TW];
    __shared__ float nrmS[TW];
    __shared__ int crow[CCH];
    int r = blockIdx.x, t = threadIdx.x;
    for (int i = t; i < IN_DIM * HID; i += 512) {
        int k = i >> 3, j = i & 7;
        wt[j * 132 + k] = W1[i];
    }
    if (t < TW) cnt[t] = 0;
    for (int i = t; i < CCH; i += 512) crow[i] = cntS_t[(size_t)r * CCH + i];
    __syncthreads();
    // histogram over this tile's region: CCH chunks x CAPS bytes (word reads, validity by count)
    const unsigned* reg = reinterpret_cast<const unsigned*>(bucket_s + (size_t)r * (CCH * CAPS));
    for (int w = t; w < CCH * (CAPS / 4); w += 512) {
        int c = w >> 5;              // CAPS/4 = 32 words per chunk
        int base = (w & 31) << 2;    // byte index within chunk run
        int cc = crow[c];
        if (base < cc) {
            unsigned wd = reg[w];
            atomicAdd(&cnt[wd & 255], 1);
            if (base + 1 < cc) atomicAdd(&cnt[(wd >> 8) & 255], 1);
            if (base + 2 < cc) atomicAdd(&cnt[(wd >> 16) & 255], 1);
            if (base + 3 < cc) atomicAdd(&cnt[wd >> 24], 1);
        }
    }
    __syncthreads();
    if (t < TW) {
        int node = r * TW + t;
        if (node < N) deg_out[node] = (float)cnt[t];
        nrmS[t] = rsqrtf(fmaxf((float)cnt[t], 1.0f));
    }
    __syncthreads();
    // conv: 8 lanes per node, 64 nodes per sweep, 4 sweeps
    int grp = t >> 3, lane = t & 7;
    #pragma unroll
    for (int sweep = 0; sweep < 4; ++sweep) {
        int nl = sweep * 64 + grp;
        int node = r * TW + nl;
        if (node < N) {
            const float4* xp = reinterpret_cast<const float4*>(x + (size_t)node * IN_DIM);
            float4 xv[4];
            #pragma unroll
            for (int m = 0; m < 4; ++m) xv[m] = xp[lane + m * 8];
            float acc[HID];
            #pragma unroll
            for (int j = 0; j < HID; ++j) acc[j] = 0.f;
            #pragma unroll
            for (int j = 0; j < HID; ++j) {
                #pragma unroll
                for (int m = 0; m < 4; ++m) {
                    float4 wv = *reinterpret_cast<const float4*>(&wt[j * 132 + lane * 4 + m * 32]);
                    acc[j] += xv[m].x * wv.x + xv[m].y * wv.y + xv[m].z * wv.z + xv[m].w * wv.w;
                }
            }
            #pragma unroll
            for (int off = 1; off < 8; off <<= 1) {
                #pragma unroll
                for (int j = 0; j < HID; ++j) acc[j] += __shfl_xor(acc[j], off, 64);
            }
            if (lane == 0) {
                float nrm = nrmS[nl];
                __half2 p0 = __floats2half2_rn(acc[0] * nrm, acc[1] * nrm);
                __half2 p1 = __floats2half2_rn(acc[2] * nrm, acc[3] * nrm);
                __half2 p2 = __floats2half2_rn(acc[4] * nrm, acc[5] * nrm);
                __half2 p3 = __floats2half2_rn(acc[6] * nrm, acc[7] * nrm);
                uint4 o;
                o.x = *reinterpret_cast<unsigned*>(&p0);
                o.y = *reinterpret_cast<unsigned*>(&p1);
                o.z = *reinterpret_cast<unsigned*>(&p2);
                o.w = *reinterpret_cast<unsigned*>(&p3);
                h4[node] = o;
            }
        }
    }
}

// ---------------- sortagg2: region compaction (wave-ballot append) + sort + agg1 ----------------
__device__ __forceinline__ void accAdd(float* acc, uint4 g) {
    __half2 q0 = *reinterpret_cast<__half2*>(&g.x);
    __half2 q1 = *reinterpret_cast<__half2*>(&g.y);
    __half2 q2 = *reinterpret_cast<__half2*>(&g.z);
    __half2 q3 = *reinterpret_cast<__half2*>(&g.w);
    float2 f0 = __half22float2(q0), f1 = __half22float2(q1);
    float2 f2 = __half22float2(q2), f3 = __half22float2(q3);
    acc[0] += f0.x; acc[1] += f0.y;
    acc[2] += f1.x; acc[3] += f1.y;
    acc[4] += f2.x; acc[5] += f2.y;
    acc[6] += f3.x; acc[7] += f3.y;
}

__global__ __launch_bounds__(512) void sortagg2_kernel(
        const unsigned int* __restrict__ bucketT, const int* __restrict__ cntD_t,
        unsigned int* __restrict__ bucketG, int* __restrict__ row_ptr,
        const uint4* __restrict__ h4, const float* __restrict__ deg_out,
        const float* __restrict__ b1, const float* __restrict__ W2,
        float* __restrict__ h2, int N) {
    __shared__ unsigned dense[TILECAP];
    __shared__ int cnt[TW], scn[TW], start[TW];
    __shared__ int crow[CCH];
    __shared__ float b1s[HID], w2s[HID];
    __shared__ int dlen_s;
    int r = blockIdx.x, t = threadIdx.x;
    if (t < TW) cnt[t] = 0;
    if (t < HID) { b1s[t] = b1[t]; w2s[t] = W2[t]; }
    if (t == 0) dlen_s = 0;
    for (int i = t; i < CCH; i += 512) crow[i] = cntD_t[(size_t)r * CCH + i];
    __syncthreads();
    // phase 1: region read -> dense compaction (wave-aggregated append) + histogram
    const unsigned* reg = bucketT + (size_t)r * (CCH * CAPD);
    int wlane = t & 63;
    for (int i = t; i < CCH * CAPD; i += 512) {
        int c = i / CAPD;
        int idx = i - c * CAPD;
        bool valid = idx < crow[c];
        unsigned v = reg[i];   // garbage if invalid; discarded below
        unsigned long long m = __ballot(valid);
        if (m) {
            int leader = __ffsll((long long)m) - 1;
            int base = 0;
            if (wlane == leader) base = atomicAdd(&dlen_s, (int)__popcll(m));
            base = __shfl(base, leader, 64);
            if (valid) {
                int pos = base + (int)__popcll(m & ((1ull << wlane) - 1ull));
                dense[pos] = v;
                atomicAdd(&cnt[v & 255u], 1);
            }
        }
    }
    __syncthreads();
    int len = dlen_s;
    // phase 2: scan of per-node counts
    if (t < TW) scn[t] = cnt[t];
    __syncthreads();
    for (int off = 1; off < TW; off <<= 1) {
        int v = 0;
        if (t < TW && t >= off) v = scn[t - off];
        __syncthreads();
        if (t < TW) scn[t] += v;
        __syncthreads();
    }
    int gbase = r * TILECAP;
    if (t < TW) {
        start[t] = scn[t] - cnt[t];
        row_ptr[r * (TW + 1) + t] = gbase + scn[t] - cnt[t];
    }
    if (t == 0) row_ptr[r * (TW + 1) + TW] = gbase + len;
    __syncthreads();
    // phase 3: slot scatter from dense LDS -> bucketG (per-tile region, L2-local)
    for (int i = t; i < len; i += 512) {
        unsigned v = dense[i];
        int p = atomicAdd(&start[v & 255u], 1);
        bucketG[gbase + p] = v >> 8;
    }
    __syncthreads();
    // phase 4: agg1, 4 lanes per node, 2 halves
    #pragma unroll
    for (int half = 0; half < 2; ++half) {
        int nl = (t >> 2) + half * 128;
        int sub = t & 3;
        int node = r * TW + nl;
        int end = scn[nl], beg = end - cnt[nl];
        float acc[HID];
        #pragma unroll
        for (int j = 0; j < HID; ++j) acc[j] = 0.f;
        for (int e = beg + sub; e < end; e += 4) accAdd(acc, h4[bucketG[gbase + e]]);
        #pragma unroll
        for (int off = 1; off < 4; off <<= 1) {
            #pragma unroll
            for (int j = 0; j < HID; ++j) acc[j] += __shfl_xor(acc[j], off, 64);
        }
        if (sub == 0 && node < N) {
            float din = (float)(end - beg);
            float nin = rsqrtf(fmaxf(din, 1.f));
            float nout = rsqrtf(fmaxf(deg_out[node], 1.f));
            float dot = 0.f;
            #pragma unroll
            for (int j = 0; j < HID; ++j) {
                float y = fmaxf(acc[j] * nin + b1s[j], 0.f);
                dot += y * w2s[j];
            }
            h2[node] = dot * nout;
        }
    }
}

// ---------------- agg2G4: 4 lanes per node over h2, fused final output ----------------
__global__ __launch_bounds__(256) void agg2G4_kernel(const unsigned int* __restrict__ bucketG,
        const int* __restrict__ row_ptr, const float* __restrict__ h2,
        const float* __restrict__ b2, float* __restrict__ out, int N) {
    int tid = blockIdx.x * 256 + threadIdx.x;
    int node = tid >> 2, sub = tid & 3;
    int r = node >> 8, tloc = node & 255;
    int s0 = row_ptr[r * (TW + 1) + tloc], s1 = row_ptr[r * (TW + 1) + tloc + 1];
    float a = 0.f;
    for (int e = s0 + sub; e < s1; e += 4) a += h2[bucketG[e]];
    a += __shfl_xor(a, 1, 64);
    a += __shfl_xor(a, 2, 64);
    if (sub == 0 && node < N) {
        float nin = rsqrtf(fmaxf((float)(s1 - s0), 1.f));
        out[node] = a * nin + b2[0];
    }
}

extern "C" void kernel_launch(void* const* d_in, const int* in_sizes, int n_in,
                              void* d_out, int out_size, void* d_ws, size_t ws_size,
                              hipStream_t stream) {
    const float* x  = (const float*)d_in[0];
    const int* src  = (const int*)d_in[1];
    const int* dst  = (const int*)d_in[2];
    const float* W1 = (const float*)d_in[3];
    const float* b1 = (const float*)d_in[4];
    const float* W2 = (const float*)d_in[5];
    const float* b2 = (const float*)d_in[6];
    float* out = (float*)d_out;

    const int N  = out_size;     // 100000
    const int E  = in_sizes[1];  // 3200000
    const int RT = (N + TW - 1) / TW;                    // 391 tiles
    const int chunk = (((E + CCH - 1) / CCH) + 3) & ~3;  // mult of 4 (int4)

    // workspace layout (regions may hold garbage in unused slots; never read as valid)
    float* ws      = (float*)d_ws;
    float* deg_out = ws;                          // N
    float* h2      = deg_out + N;                 // N
    int*   cntS_t  = (int*)(h2 + N);              // RT*CCH (tile-major)
    int*   cntD_t  = cntS_t + (size_t)RT * CCH;   // RT*CCH
    int*   row_ptr = cntD_t + (size_t)RT * CCH;   // RT*(TW+1)
    unsigned int* bucketG = (unsigned int*)(row_ptr + (size_t)RT * (TW + 1));  // RT*TILECAP
    uint4* h4 = (uint4*)(((uintptr_t)(bucketG + (size_t)RT * TILECAP) + 15) & ~(uintptr_t)15);  // N
    unsigned int* bucketT = (unsigned int*)(h4 + N);                // RT*CCH*CAPD
    unsigned char* bucket_s = (unsigned char*)(bucketT + (size_t)RT * CCH * CAPD);  // RT*CCH*CAPS

    scatterAB2_kernel<<<CCH, 1024, 0, stream>>>(src, dst, bucket_s, bucketT,
                                                cntS_t, cntD_t, E, RT, chunk);
    conv1deg2_kernel<<<RT, 512, 0, stream>>>(bucket_s, cntS_t, x, W1, deg_out, h4, N);
    sortagg2_kernel<<<RT, 512, 0, stream>>>(bucketT, cntD_t, bucketG, row_ptr,
                                            h4, deg_out, b1, W2, h2, N);
    agg2G4_kernel<<<RT * 4, 256, 0, stream>>>(bucketG, row_ptr, h2, b2, out, N);
}

// Round 15
// 110.252 us; speedup vs baseline: 1.2628x; 1.2628x over previous
//
#include <hip/hip_runtime.h>
#include <hip/hip_bf16.h>
#include <hip/hip_fp16.h>

#define IN_DIM 128
#define HID 8
#define TW 256       // node tile width (sort + CSR granularity)
#define MAXT 512     // max tiles (N<=131072)
#define CCH 256      // edge chunks (one 1024-thread block each; 256 = 8 XCDs * 32)
#define CAP 12288    // LDS sorted-run capacity (uints); tile runs ~8200 for this input

// ---------------- pass1AB: per-chunk src-tile AND dst-tile histograms ----------------
// Same XCD swizzle as scatterAB so each chunk's src/dst bytes are read on the same
// XCD in both kernels (cross-kernel L2 reuse of the 51 MB index stream).
__global__ __launch_bounds__(1024) void pass1AB_kernel(const int* __restrict__ src, const int* __restrict__ dst,
        int* __restrict__ cntS, int* __restrict__ cntD, int E, int RT, int chunk) {
    __shared__ int cs[MAXT], cd[MAXT];
    int t = threadIdx.x;
    int c = ((blockIdx.x & 7) << 5) | (blockIdx.x >> 3);
    for (int i = t; i < RT; i += 1024) { cs[i] = 0; cd[i] = 0; }
    __syncthreads();
    int lo = c * chunk, hi = min(lo + chunk, E);
    if (lo < hi) {
        const int4* s4 = reinterpret_cast<const int4*>(src);
        const int4* d4 = reinterpret_cast<const int4*>(dst);
        int q0 = lo >> 2, q1 = hi >> 2;
        for (int q = q0 + t; q < q1; q += 1024) {
            int4 s = s4[q], d = d4[q];
            atomicAdd(&cs[s.x >> 8], 1); atomicAdd(&cs[s.y >> 8], 1);
            atomicAdd(&cs[s.z >> 8], 1); atomicAdd(&cs[s.w >> 8], 1);
            atomicAdd(&cd[d.x >> 8], 1); atomicAdd(&cd[d.y >> 8], 1);
            atomicAdd(&cd[d.z >> 8], 1); atomicAdd(&cd[d.w >> 8], 1);
        }
        for (int i = (q1 << 2) + t; i < hi; i += 1024) {
            atomicAdd(&cs[src[i] >> 8], 1);
            atomicAdd(&cd[dst[i] >> 8], 1);
        }
    }
    __syncthreads();
    for (int i = t; i < RT; i += 1024) {
        cntS[(size_t)c * RT + i] = cs[i];
        cntD[(size_t)c * RT + i] = cd[i];
    }
}

// ---------------- scan1: per-tile exclusive scan over 256 chunks (S and D via blockIdx.y) ----------------
__global__ __launch_bounds__(256) void scan1_kernel(int* __restrict__ cntS, int* __restrict__ cntD,
        int* __restrict__ totS, int* __restrict__ totD, int RT) {
    int r = blockIdx.x;
    int* cnt = blockIdx.y ? cntD : cntS;
    int* tot = blockIdx.y ? totD : totS;
    __shared__ int sh[256];
    int t = threadIdx.x;
    int e = cnt[(size_t)t * RT + r];
    sh[t] = e;
    __syncthreads();
    for (int off = 1; off < 256; off <<= 1) {
        int v = (t >= off) ? sh[t - off] : 0;
        __syncthreads();
        sh[t] += v;
        __syncthreads();
    }
    cnt[(size_t)t * RT + r] = sh[t] - e;
    if (t == 255) tot[r] = sh[255];
}

// ---------------- scan2: exclusive scan of tile totals -> bases (S and D via blockIdx.x) ----------------
__global__ __launch_bounds__(256) void scan2_kernel(const int* __restrict__ totS, const int* __restrict__ totD,
        int* __restrict__ baseS, int* __restrict__ baseD, int RT) {
    const int* tot = blockIdx.x ? totD : totS;
    int* base = blockIdx.x ? baseD : baseS;
    __shared__ int sh[256];
    int t = threadIdx.x;
    int K = (RT + 255) / 256;   // <=2
    int vals[4];
    int s = 0;
    for (int k = 0; k < K; ++k) {
        int i = t * K + k;
        int v = (i < RT) ? tot[i] : 0;
        vals[k] = v; s += v;
    }
    sh[t] = s;
    __syncthreads();
    for (int off = 1; off < 256; off <<= 1) {
        int v = (t >= off) ? sh[t - off] : 0;
        __syncthreads();
        sh[t] += v;
        __syncthreads();
    }
    int exc = sh[t] - s;
    for (int k = 0; k < K; ++k) {
        int i = t * K + k;
        if (i < RT) base[i] = exc;
        exc += vals[k];
    }
    if (t == 255) base[RT] = sh[255];
}

// ---------------- scatterAB: src-tile byte locals + dst-tile packed records ----------------
// XCD-affinity swizzle keeps memory-adjacent chunks on one XCD (run-boundary lines stay local).
__global__ __launch_bounds__(1024) void scatterAB_kernel(const int* __restrict__ src, const int* __restrict__ dst,
        const int* __restrict__ cntS, const int* __restrict__ cntD,
        const int* __restrict__ baseS, const int* __restrict__ baseD,
        unsigned char* __restrict__ bucket_s, unsigned int* __restrict__ bucketT,
        int E, int RT, int chunk) {
    __shared__ int os[MAXT], od[MAXT];
    int t = threadIdx.x;
    int c = ((blockIdx.x & 7) << 5) | (blockIdx.x >> 3);   // bid -> chunk, same-XCD adjacency
    for (int i = t; i < RT; i += 1024) {
        os[i] = baseS[i] + cntS[(size_t)c * RT + i];
        od[i] = baseD[i] + cntD[(size_t)c * RT + i];
    }
    __syncthreads();
    int lo = c * chunk, hi = min(lo + chunk, E);
    if (lo >= hi) return;
    const int4* s4 = reinterpret_cast<const int4*>(src);
    const int4* d4 = reinterpret_cast<const int4*>(dst);
    int q0 = lo >> 2, q1 = hi >> 2;
    for (int q = q0 + t; q < q1; q += 1024) {
        int4 s = s4[q], d = d4[q];
        int p;
        p = atomicAdd(&os[s.x >> 8], 1); bucket_s[p] = (unsigned char)(s.x & 255);
        p = atomicAdd(&os[s.y >> 8], 1); bucket_s[p] = (unsigned char)(s.y & 255);
        p = atomicAdd(&os[s.z >> 8], 1); bucket_s[p] = (unsigned char)(s.z & 255);
        p = atomicAdd(&os[s.w >> 8], 1); bucket_s[p] = (unsigned char)(s.w & 255);
        p = atomicAdd(&od[d.x >> 8], 1); bucketT[p] = ((unsigned)s.x << 8) | (unsigned)(d.x & 255);
        p = atomicAdd(&od[d.y >> 8], 1); bucketT[p] = ((unsigned)s.y << 8) | (unsigned)(d.y & 255);
        p = atomicAdd(&od[d.z >> 8], 1); bucketT[p] = ((unsigned)s.z << 8) | (unsigned)(d.z & 255);
        p = atomicAdd(&od[d.w >> 8], 1); bucketT[p] = ((unsigned)s.w << 8) | (unsigned)(d.w & 255);
    }
    for (int i = (q1 << 2) + t; i < hi; i += 1024) {
        int s = src[i], d = dst[i];
        int p = atomicAdd(&os[s >> 8], 1);
        bucket_s[p] = (unsigned char)(s & 255);
        p = atomicAdd(&od[d >> 8], 1);
        bucketT[p] = ((unsigned)s << 8) | (unsigned)(d & 255);
    }
}

// ---------------- conv1deg: fused per-src-tile degout + conv1 -> deg_out, h4 (512 thr) ----------------
__global__ __launch_bounds__(512) void conv1deg_kernel(
        const unsigned char* __restrict__ bucket_s, const int* __restrict__ baseS,
        const float* __restrict__ x, const float* __restrict__ W1,
        float* __restrict__ deg_out, uint4* __restrict__ h4, int N) {
    __shared__ float wt[HID * 132];
    __shared__ int cnt[TW];
    __shared__ float nrmS[TW];
    int r = blockIdx.x, t = threadIdx.x;
    for (int i = t; i < IN_DIM * HID; i += 512) {
        int k = i >> 3, j = i & 7;
        wt[j * 132 + k] = W1[i];
    }
    if (t < TW) cnt[t] = 0;
    __syncthreads();
    int lo = baseS[r], hi = baseS[r + 1];
    int a0 = min((lo + 3) & ~3, hi), a1 = max(hi & ~3, a0);
    for (int i = lo + t; i < a0; i += 512) atomicAdd(&cnt[bucket_s[i]], 1);
    const unsigned* w4 = reinterpret_cast<const unsigned*>(bucket_s);
    for (int q = (a0 >> 2) + t; q < (a1 >> 2); q += 512) {
        unsigned w = w4[q];
        atomicAdd(&cnt[w & 255], 1);
        atomicAdd(&cnt[(w >> 8) & 255], 1);
        atomicAdd(&cnt[(w >> 16) & 255], 1);
        atomicAdd(&cnt[w >> 24], 1);
    }
    for (int i = a1 + t; i < hi; i += 512) atomicAdd(&cnt[bucket_s[i]], 1);
    __syncthreads();
    if (t < TW) {
        int node = r * TW + t;
        if (node < N) deg_out[node] = (float)cnt[t];
        nrmS[t] = rsqrtf(fmaxf((float)cnt[t], 1.0f));
    }
    __syncthreads();
    // conv: 8 lanes per node, 64 nodes per sweep, 4 sweeps
    int grp = t >> 3, lane = t & 7;
    #pragma unroll
    for (int sweep = 0; sweep < 4; ++sweep) {
        int nl = sweep * 64 + grp;
        int node = r * TW + nl;
        if (node < N) {
            const float4* xp = reinterpret_cast<const float4*>(x + (size_t)node * IN_DIM);
            float4 xv[4];
            #pragma unroll
            for (int m = 0; m < 4; ++m) xv[m] = xp[lane + m * 8];
            float acc[HID];
            #pragma unroll
            for (int j = 0; j < HID; ++j) acc[j] = 0.f;
            #pragma unroll
            for (int j = 0; j < HID; ++j) {
                #pragma unroll
                for (int m = 0; m < 4; ++m) {
                    float4 wv = *reinterpret_cast<const float4*>(&wt[j * 132 + lane * 4 + m * 32]);
                    acc[j] += xv[m].x * wv.x + xv[m].y * wv.y + xv[m].z * wv.z + xv[m].w * wv.w;
                }
            }
            #pragma unroll
            for (int off = 1; off < 8; off <<= 1) {
                #pragma unroll
                for (int j = 0; j < HID; ++j) acc[j] += __shfl_xor(acc[j], off, 64);
            }
            if (lane == 0) {
                float nrm = nrmS[nl];
                __half2 p0 = __floats2half2_rn(acc[0] * nrm, acc[1] * nrm);
                __half2 p1 = __floats2half2_rn(acc[2] * nrm, acc[3] * nrm);
                __half2 p2 = __floats2half2_rn(acc[4] * nrm, acc[5] * nrm);
                __half2 p3 = __floats2half2_rn(acc[6] * nrm, acc[7] * nrm);
                uint4 o;
                o.x = *reinterpret_cast<unsigned*>(&p0);
                o.y = *reinterpret_cast<unsigned*>(&p1);
                o.z = *reinterpret_cast<unsigned*>(&p2);
                o.w = *reinterpret_cast<unsigned*>(&p3);
                h4[node] = o;
            }
        }
    }
}

// ---------------- sortagg1: fused within-tile sort + layer-1 aggregation ----------------
__device__ __forceinline__ void accAdd(float* acc, uint4 g) {
    __half2 q0 = *reinterpret_cast<__half2*>(&g.x);
    __half2 q1 = *reinterpret_cast<__half2*>(&g.y);
    __half2 q2 = *reinterpret_cast<__half2*>(&g.z);
    __half2 q3 = *reinterpret_cast<__half2*>(&g.w);
    float2 f0 = __half22float2(q0), f1 = __half22float2(q1);
    float2 f2 = __half22float2(q2), f3 = __half22float2(q3);
    acc[0] += f0.x; acc[1] += f0.y;
    acc[2] += f1.x; acc[3] += f1.y;
    acc[4] += f2.x; acc[5] += f2.y;
    acc[6] += f3.x; acc[7] += f3.y;
}

__global__ __launch_bounds__(512) void sortagg1_kernel(
        const unsigned int* __restrict__ bucketT, const int* __restrict__ baseD,
        unsigned int* __restrict__ bucketG, int* __restrict__ row_ptr,
        const uint4* __restrict__ h4, const float* __restrict__ deg_out,
        const float* __restrict__ b1, const float* __restrict__ W2,
        float* __restrict__ h2, int E, int RT, int N) {
    __shared__ unsigned sorted[CAP];
    __shared__ int cnt[TW], scn[TW], start[TW];
    __shared__ float b1s[HID], w2s[HID];
    int r = blockIdx.x, t = threadIdx.x;
    if (t < TW) cnt[t] = 0;
    if (t < HID) { b1s[t] = b1[t]; w2s[t] = W2[t]; }
    __syncthreads();
    int lo = baseD[r], hi = baseD[r + 1], len = hi - lo;
    // phase 1: histogram of dst locals (sequential global read)
    for (int i = lo + t; i < hi; i += 512) atomicAdd(&cnt[bucketT[i] & 255u], 1);
    __syncthreads();
    // phase 2: scan
    if (t < TW) scn[t] = cnt[t];
    __syncthreads();
    for (int off = 1; off < TW; off <<= 1) {
        int v = 0;
        if (t < TW && t >= off) v = scn[t - off];
        __syncthreads();
        if (t < TW) scn[t] += v;
        __syncthreads();
    }
    if (t < TW) {
        start[t] = scn[t] - cnt[t];
        row_ptr[r * TW + t] = lo + scn[t] - cnt[t];
    }
    if (r == 0 && t == 0) row_ptr[RT * TW] = E;
    __syncthreads();
    bool fits = (len <= CAP);
    // phase 3: scatter to sorted order (LDS if it fits, else global)
    if (fits) {
        for (int i = lo + t; i < hi; i += 512) {
            unsigned v = bucketT[i];
            int p = atomicAdd(&start[v & 255u], 1);
            sorted[p] = v >> 8;
        }
        __syncthreads();
        // phase 4: sequential coalesced bucketG write (for agg2)
        for (int i = t; i < len; i += 512) bucketG[lo + i] = sorted[i];
    } else {
        for (int i = lo + t; i < hi; i += 512) {
            unsigned v = bucketT[i];
            int p = atomicAdd(&start[v & 255u], 1);
            bucketG[lo + p] = v >> 8;
        }
        __syncthreads();
    }
    // phase 5: aggregation, 4 lanes per node, 2 halves (512 threads / 256 nodes)
    #pragma unroll
    for (int half = 0; half < 2; ++half) {
        int nl = (t >> 2) + half * 128;
        int sub = t & 3;
        int node = r * TW + nl;
        int end = scn[nl], beg = end - cnt[nl];
        float acc[HID];
        #pragma unroll
        for (int j = 0; j < HID; ++j) acc[j] = 0.f;
        if (fits) {
            for (int e = beg + sub; e < end; e += 4) accAdd(acc, h4[sorted[e]]);
        } else {
            for (int e = beg + sub; e < end; e += 4) accAdd(acc, h4[bucketG[lo + e]]);
        }
        #pragma unroll
        for (int off = 1; off < 4; off <<= 1) {
            #pragma unroll
            for (int j = 0; j < HID; ++j) acc[j] += __shfl_xor(acc[j], off, 64);
        }
        if (sub == 0 && node < N) {
            float din = (float)(end - beg);
            float nin = rsqrtf(fmaxf(din, 1.f));
            float nout = rsqrtf(fmaxf(deg_out[node], 1.f));
            float dot = 0.f;
            #pragma unroll
            for (int j = 0; j < HID; ++j) {
                float y = fmaxf(acc[j] * nin + b1s[j], 0.f);
                dot += y * w2s[j];
            }
            h2[node] = dot * nout;
        }
    }
}

// ---------------- agg2G4: 4 lanes per node over h2, fused final output ----------------
__global__ __launch_bounds__(256) void agg2G4_kernel(const unsigned int* __restrict__ bucketG,
        const int* __restrict__ row_ptr, const float* __restrict__ h2,
        const float* __restrict__ b2, float* __restrict__ out, int N) {
    int tid = blockIdx.x * 256 + threadIdx.x;
    int node = tid >> 2, sub = tid & 3;
    int s0 = row_ptr[node], s1 = row_ptr[node + 1];
    float a = 0.f;
    for (int e = s0 + sub; e < s1; e += 4) a += h2[bucketG[e]];
    a += __shfl_xor(a, 1, 64);
    a += __shfl_xor(a, 2, 64);
    if (sub == 0 && node < N) {
        float nin = rsqrtf(fmaxf((float)(s1 - s0), 1.f));
        out[node] = a * nin + b2[0];
    }
}

extern "C" void kernel_launch(void* const* d_in, const int* in_sizes, int n_in,
                              void* d_out, int out_size, void* d_ws, size_t ws_size,
                              hipStream_t stream) {
    const float* x  = (const float*)d_in[0];
    const int* src  = (const int*)d_in[1];
    const int* dst  = (const int*)d_in[2];
    const float* W1 = (const float*)d_in[3];
    const float* b1 = (const float*)d_in[4];
    const float* W2 = (const float*)d_in[5];
    const float* b2 = (const float*)d_in[6];
    float* out = (float*)d_out;

    const int N  = out_size;     // 100000
    const int E  = in_sizes[1];  // 3200000
    const int RT = (N + TW - 1) / TW;                    // 391 tiles
    const int chunk = (((E + CCH - 1) / CCH) + 3) & ~3;  // mult of 4 (int4)

    // workspace layout (every region fully written before read each call; no memset)
    float* ws      = (float*)d_ws;
    float* deg_out = ws;                        // N
    float* h2      = deg_out + N;               // N
    int*   cntS    = (int*)(h2 + N);            // CCH*RT
    int*   cntD    = cntS + (size_t)CCH * RT;   // CCH*RT
    int*   totS    = cntD + (size_t)CCH * RT;   // RT
    int*   baseS   = totS + RT;                 // RT+1
    int*   totD    = baseS + RT + 1;            // RT
    int*   baseD   = totD + RT;                 // RT+1
    int*   row_ptr = baseD + RT + 1;            // RT*TW+1
    unsigned int* bucketT = (unsigned int*)(row_ptr + (size_t)RT * TW + 1);  // E
    unsigned int* bucketG = bucketT + E;        // E
    uint4* h4 = (uint4*)(((uintptr_t)(bucketG + E) + 15) & ~(uintptr_t)15);  // N
    unsigned char* bucket_s = (unsigned char*)(h4 + N);  // E bytes

    pass1AB_kernel<<<CCH, 1024, 0, stream>>>(src, dst, cntS, cntD, E, RT, chunk);
    scan1_kernel<<<dim3(RT, 2), 256, 0, stream>>>(cntS, cntD, totS, totD, RT);
    scan2_kernel<<<2, 256, 0, stream>>>(totS, totD, baseS, baseD, RT);
    scatterAB_kernel<<<CCH, 1024, 0, stream>>>(src, dst, cntS, cntD, baseS, baseD,
                                               bucket_s, bucketT, E, RT, chunk);
    conv1deg_kernel<<<RT, 512, 0, stream>>>(bucket_s, baseS, x, W1, deg_out, h4, N);
    sortagg1_kernel<<<RT, 512, 0, stream>>>(bucketT, baseD, bucketG, row_ptr,
                                            h4, deg_out, b1, W2, h2, E, RT, N);
    agg2G4_kernel<<<RT * 4, 256, 0, stream>>>(bucketG, row_ptr, h2, b2, out, N);
}